// Round 15
// baseline (253.794 us; speedup 1.0000x reference)
//
#include <hip/hip_runtime.h>
#include <math.h>

#define HID 50
#define TT  512
#define BT  16      // batch per block (= MFMA N)
#define NTH 512     // 8 waves, 2 per SIMD (R24-proven pairing)
#define HS  72      // H plane row stride in shorts (144 B, 16B-aligned)
#define L2E 1.44269504088896f
#define K2C 2.88539008177793f   // 2*log2(e)

typedef __attribute__((ext_vector_type(8))) short bf16x8;
typedef __attribute__((ext_vector_type(4))) float f32x4;

__device__ __forceinline__ unsigned short bf16_rtne(float f) {
    unsigned u = __float_as_uint(f);
    u = (u + 0x7FFFu + ((u >> 16) & 1u)) >> 16;
    return (unsigned short)u;
}
__device__ __forceinline__ float bf16_f32(unsigned short s) {
    return __uint_as_float(((unsigned)s) << 16);
}

// R27: trans-balanced 8-wave layout. R25/R26 proved 7 waves leaves a lone
// wave per SIMD (exposed latency, VALUBusy 47->39). R24's flaw: pairing
// put 4 GATES (224 trans-cy) on 3 SIMDs while S3 had 112, AND wave 6
// wasted a full GATES + 2 MFMAs on pure-phantom tile 13.
// New map (units 0..49 each exactly once; pairs = {wv, wv+4}):
//   w0..w3: 2 full tiles (T0..T7, units 0..31)          [161 issue-cy]
//   w4: T8 (32..35) + mixed-M (y rows 0,1 raw hi/lo W_out; units 48,49
//       rows 4..11; GATES exec-masked to quads 1,2; R26-proven layout)
//       + y-store (quad-0 lanes)                         [~130]
//   w5: T9 (36..39) + x-duty (quad-3 lanes)              [~112]
//   w6: T10 (40..43); w7: T11 (44..47)                   [~87]
// Per-SIMD pairs: {291, 273, 248, 248} vs R24 {322,322,322,200}.
// Carries: lgkm-only barrier (R20), unroll x2 + hoisted ptrs + cvt_pk
// (R21), chained MFMA (R23), ILP-2 + shared B read (R24), mixed-M (R26).
//
// Math (gate A rows pre-scaled by log2e for i,f,o / 2*log2e for g; y RAW):
//   Ei=2^-i', Ef=2^-f', Eg=2^g', Eo=2^-o'
//   cs = [cs*(1+Ei)(1+Eg) + K2*(Eg-1)*(1+Ef)] * rcp((1+Ef)(1+Ei)(1+Eg))
//   Ec = 2^cs;  h = (Ec-1) * rcp((1+Eo)(1+Ec))
// K-slots: 0..49 = s*W_hh | 50 = (s*Wih)_hi (x_hi) | 51 = (s*bias)_hi (1.0)
//          52 = (s*Wih)_hi (x_lo) | 53 = (s*bias)_lo (1.0) | 54 = (s*Wih)_lo (x_hi)
//          55..63 = zero (never written after init)
__global__ __launch_bounds__(NTH, 1) void lstm_mfma20_kernel(
    const float* __restrict__ x,      // [B, T]
    const float* __restrict__ W_ih,   // [200, 1]
    const float* __restrict__ W_hh,   // [200, 50]
    const float* __restrict__ b_ih,   // [200]
    const float* __restrict__ b_hh,   // [200]
    const float* __restrict__ W_out,  // [1, 50]
    const float* __restrict__ b_out,  // [1]
    float* __restrict__ out)          // [B, T]
{
    const int tid  = threadIdx.x;
    const int lane = tid & 63;
    const int wv   = tid >> 6;       // 0..7
    const int col  = lane & 15;      // A-m / B-n(batch) / D-col(batch)
    const int quad = lane >> 4;      // k-octet / D row-group

    __shared__ __align__(16) unsigned short Hh[2][BT][HS];

    // zero both H buffers (k-slots 55..63 + pads stay 0)
    for (int i = tid; i < 2 * BT * HS; i += NTH)
        (&Hh[0][0][0])[i] = 0;

    // persistent A fragments: [tile][kk] (single plane, PRE-SCALED rows)
    bf16x8 Ah[2][2];
    float cs0 = 0.f, cs1 = 0.f;
    // primary h slot; w0..w3 second slot s1; w4 masked slot sM
    const int s0 = (wv < 4) ? wv * 8 + quad : wv * 4 + 16 + quad;
    const int s1 = wv * 8 + 4 + quad;          // class-A only (<= 35)
    const int sM = (quad == 1) ? 48 : 49;      // w4, used under q1/q2 mask

#define FILL_GATE_ROW(DST, GH)                                                \
    do {                                                                      \
        const int u_  = (GH) >> 2;                                            \
        const int ty_ = (GH) & 3;                                             \
        const int og_ = ty_ * HID + u_;                                       \
        const float sc_ = (ty_ == 2) ? K2C : L2E;                             \
        _Pragma("unroll")                                                     \
        for (int kk = 0; kk < 2; ++kk) {                                      \
            _Pragma("unroll")                                                 \
            for (int j = 0; j < 8; ++j) {                                     \
                const int k = kk * 32 + quad * 8 + j;                         \
                float v = 0.f;                                                \
                if (k < HID)      v = sc_ * W_hh[og_ * HID + k];              \
                else if (k == 50) v = sc_ * W_ih[og_];                        \
                else if (k == 51) v = sc_ * (b_ih[og_] + b_hh[og_]);          \
                else if (k == 52) v = sc_ * W_ih[og_];                        \
                else if (k == 53) {                                           \
                    const float sb = sc_ * (b_ih[og_] + b_hh[og_]);           \
                    v = sb - bf16_f32(bf16_rtne(sb));                         \
                } else if (k == 54) {                                         \
                    const float sw = sc_ * W_ih[og_];                         \
                    v = sw - bf16_f32(bf16_rtne(sw));                         \
                }                                                             \
                (DST)[kk][j] = (short)bf16_rtne(v);                           \
            }                                                                 \
        }                                                                     \
    } while (0)

    if (wv < 4) {
        FILL_GATE_ROW(Ah[0], (wv * 2) * 16 + col);       // T(2wv), units 8wv..
        FILL_GATE_ROW(Ah[1], (wv * 2 + 1) * 16 + col);   // T(2wv+1)
    } else if (wv == 4) {
        FILL_GATE_ROW(Ah[0], 8 * 16 + col);              // T8, units 32..35
        // Ah[1] = mixed-M (R26-proven): rows 0,1 = y hi/lo RAW (k<50);
        // rows 4..7 = unit 48; rows 8..11 = unit 49; rest zero.
        #pragma unroll
        for (int kk = 0; kk < 2; ++kk) {
            #pragma unroll
            for (int j = 0; j < 8; ++j) {
                const int k = kk * 32 + quad * 8 + j;
                float v = 0.f;
                if (col < 2) {
                    if (k < HID) {
                        const float w = W_out[k];
                        v = (col == 0) ? w : w - bf16_f32(bf16_rtne(w));
                    }
                } else if (col >= 4 && col < 12) {
                    const int u_  = (col < 8) ? 48 : 49;
                    const int ty_ = col & 3;
                    const int og_ = ty_ * HID + u_;
                    const float sc_ = (ty_ == 2) ? K2C : L2E;
                    if (k < HID)      v = sc_ * W_hh[og_ * HID + k];
                    else if (k == 50) v = sc_ * W_ih[og_];
                    else if (k == 51) v = sc_ * (b_ih[og_] + b_hh[og_]);
                    else if (k == 52) v = sc_ * W_ih[og_];
                    else if (k == 53) {
                        const float sb = sc_ * (b_ih[og_] + b_hh[og_]);
                        v = sb - bf16_f32(bf16_rtne(sb));
                    } else if (k == 54) {
                        const float sw = sc_ * W_ih[og_];
                        v = sw - bf16_f32(bf16_rtne(sw));
                    }
                }
                Ah[1][kk][j] = (short)bf16_rtne(v);
            }
        }
    } else {
        FILL_GATE_ROW(Ah[0], (wv + 4) * 16 + col);       // T9/T10/T11
        #pragma unroll
        for (int kk = 0; kk < 2; ++kk)
            #pragma unroll
            for (int j = 0; j < 8; ++j) Ah[1][kk][j] = 0;
    }
#undef FILL_GATE_ROW

    const float bo = b_out[0];
    float* yout = out + (size_t)blockIdx.x * BT * TT + (size_t)col * TT;

    // x pipeline state (w5, quad-3 lanes own batch b = col)
    const float* xrow = x + (size_t)(blockIdx.x * BT + col) * TT;
    float xa = 0.f;
    if (wv == 5 && lane >= 48)
        xa = xrow[1];                            // x[b][1] for step t=0's write

    __syncthreads();    // zeroed H visible

    // buffer-0 slots for t=0: x_0 hi/lo + bias-1.0 markers (packed b32 writes)
    if (tid < BT) {
        const float x0 = x[(size_t)(blockIdx.x * BT + tid) * TT];
        const unsigned short hx = bf16_rtne(x0);
        const unsigned short lx = bf16_rtne(x0 - bf16_f32(hx));
        unsigned* row32 = (unsigned*)&Hh[0][tid][0];
        row32[25] = (unsigned)hx | (0x3F80u << 16);   // k=50,51
        row32[26] = (unsigned)lx | (0x3F80u << 16);   // k=52,53
        Hh[0][tid][54] = hx;                          // k=54
    }
    __syncthreads();

    // hoisted per-lane pointers (loop-invariant)
    const unsigned short* rdA = &Hh[0][col][quad * 8];   // read plane 0
    const unsigned short* rdB = &Hh[1][col][quad * 8];   // read plane 1
    unsigned short* wrA0 = &Hh[1][col][s0];              // write when reading 0
    unsigned short* wrA1 = &Hh[1][col][s1];
    unsigned short* wrAM = &Hh[1][col][sM];
    unsigned short* wrB0 = &Hh[0][col][s0];              // write when reading 1
    unsigned short* wrB1 = &Hh[0][col][s1];
    unsigned short* wrBM = &Hh[0][col][sM];
    unsigned* xwA = (unsigned*)&Hh[1][col][0];
    unsigned* xwB = (unsigned*)&Hh[0][col][0];
    const f32x4 z = {0.f, 0.f, 0.f, 0.f};

#define GATES(ACC, CS, HOUT)                                                  \
    do {                                                                      \
        const float Ei = __builtin_amdgcn_exp2f(-(ACC).x);                    \
        const float Ef = __builtin_amdgcn_exp2f(-(ACC).y);                    \
        const float Eg = __builtin_amdgcn_exp2f((ACC).z);                     \
        const float Eo = __builtin_amdgcn_exp2f(-(ACC).w);                    \
        const float DIG = (1.f + Ei) * (1.f + Eg);                            \
        const float DF  = 1.f + Ef;                                           \
        const float t1  = fmaf(K2C, Eg, -K2C);                                \
        const float num = fmaf((CS), DIG, t1 * DF);                           \
        (CS) = num * __builtin_amdgcn_rcpf(DF * DIG);                         \
        const float Ec = __builtin_amdgcn_exp2f(CS);                          \
        (HOUT) = (Ec - 1.f) *                                                 \
                 __builtin_amdgcn_rcpf((1.f + Eo) * (1.f + Ec));              \
    } while (0)

#define LSTM_STEP(RD, WR0, WR1, WRM, XW, TI)                                  \
    do {                                                                      \
        const bf16x8 B0 = *(const bf16x8*)(RD);                               \
        const bf16x8 B1 = *(const bf16x8*)((RD) + 32);                        \
        if (wv < 4) {                                                         \
            f32x4 a0 = __builtin_amdgcn_mfma_f32_16x16x32_bf16(Ah[0][0], B0, z, 0, 0, 0); \
            f32x4 a1 = __builtin_amdgcn_mfma_f32_16x16x32_bf16(Ah[1][0], B0, z, 0, 0, 0); \
            a0 = __builtin_amdgcn_mfma_f32_16x16x32_bf16(Ah[0][1], B1, a0, 0, 0, 0); \
            a1 = __builtin_amdgcn_mfma_f32_16x16x32_bf16(Ah[1][1], B1, a1, 0, 0, 0); \
            float h0, h1;                                                     \
            GATES(a0, cs0, h0);                                               \
            GATES(a1, cs1, h1);                                               \
            unsigned hpk;                                                     \
            asm("v_cvt_pk_bf16_f32 %0, %1, %2" : "=v"(hpk) : "v"(h0), "v"(h1)); \
            *(WR0) = (unsigned short)(hpk & 0xFFFFu);                         \
            *(WR1) = (unsigned short)(hpk >> 16);                             \
        } else if (wv == 4) {                                                 \
            f32x4 a0 = __builtin_amdgcn_mfma_f32_16x16x32_bf16(Ah[0][0], B0, z, 0, 0, 0); \
            f32x4 a1 = __builtin_amdgcn_mfma_f32_16x16x32_bf16(Ah[1][0], B0, z, 0, 0, 0); \
            a0 = __builtin_amdgcn_mfma_f32_16x16x32_bf16(Ah[0][1], B1, a0, 0, 0, 0); \
            a1 = __builtin_amdgcn_mfma_f32_16x16x32_bf16(Ah[1][1], B1, a1, 0, 0, 0); \
            float h0;                                                         \
            GATES(a0, cs0, h0);                                               \
            unsigned hpk;                                                     \
            asm("v_cvt_pk_bf16_f32 %0, %1, %2" : "=v"(hpk) : "v"(h0), "v"(h0)); \
            *(WR0) = (unsigned short)(hpk & 0xFFFFu);                         \
            if (quad == 1 || quad == 2) {  /* M GATES: units 48,49 only */    \
                float h1;                                                     \
                GATES(a1, cs1, h1);                                           \
                unsigned hpm;                                                 \
                asm("v_cvt_pk_bf16_f32 %0, %1, %2" : "=v"(hpm) : "v"(h1), "v"(h1)); \
                *(WRM) = (unsigned short)(hpm & 0xFFFFu);                     \
            }                                                                 \
            if (lane < 16 && (TI) > 0)                                        \
                yout[(TI) - 1] = a1.x + a1.y + bo;                            \
        } else {                                                              \
            if (wv == 5 && lane >= 48) {                                      \
                const unsigned short hx = bf16_rtne(xa);                      \
                const unsigned short lx = bf16_rtne(xa - bf16_f32(hx));       \
                (XW)[25] = (unsigned)hx | (0x3F80u << 16);                    \
                (XW)[26] = (unsigned)lx | (0x3F80u << 16);                    \
                ((unsigned short*)(XW))[54] = hx;                             \
                xa = xrow[((TI) + 2 < TT) ? (TI) + 2 : TT - 1];               \
            }                                                                 \
            f32x4 a0 = __builtin_amdgcn_mfma_f32_16x16x32_bf16(Ah[0][0], B0, z, 0, 0, 0); \
            a0 = __builtin_amdgcn_mfma_f32_16x16x32_bf16(Ah[0][1], B1, a0, 0, 0, 0); \
            float h0;                                                         \
            GATES(a0, cs0, h0);                                               \
            unsigned hpk;                                                     \
            asm("v_cvt_pk_bf16_f32 %0, %1, %2" : "=v"(hpk) : "v"(h0), "v"(h0)); \
            *(WR0) = (unsigned short)(hpk & 0xFFFFu);                         \
        }                                                                     \
    } while (0)

    for (int t = 0; t < TT; t += 2) {
        LSTM_STEP(rdA, wrA0, wrA1, wrAM, xwA, t);      // read plane 0
        asm volatile("s_waitcnt lgkmcnt(0)\n\ts_barrier" ::: "memory");
        LSTM_STEP(rdB, wrB0, wrB1, wrBM, xwB, t + 1);  // read plane 1
        asm volatile("s_waitcnt lgkmcnt(0)\n\ts_barrier" ::: "memory");
    }
#undef LSTM_STEP
#undef GATES

    // epilogue: y_{TT-1} from plane 0 (h_{511}) via w4's M chain
    if (wv == 4) {
        const bf16x8 B0 = *(const bf16x8*)rdA;
        const bf16x8 B1 = *(const bf16x8*)(rdA + 32);
        f32x4 a1 = __builtin_amdgcn_mfma_f32_16x16x32_bf16(Ah[1][0], B0, z, 0, 0, 0);
        a1 = __builtin_amdgcn_mfma_f32_16x16x32_bf16(Ah[1][1], B1, a1, 0, 0, 0);
        if (lane < 16)
            yout[TT - 1] = a1.x + a1.y + bo;
    }
}

extern "C" void kernel_launch(void* const* d_in, const int* in_sizes, int n_in,
                              void* d_out, int out_size, void* d_ws, size_t ws_size,
                              hipStream_t stream) {
    const float* x     = (const float*)d_in[0];
    const float* W_ih  = (const float*)d_in[1];
    const float* W_hh  = (const float*)d_in[2];
    const float* b_ih  = (const float*)d_in[3];
    const float* b_hh  = (const float*)d_in[4];
    const float* W_out = (const float*)d_in[5];
    const float* b_out = (const float*)d_in[6];
    float* out = (float*)d_out;

    const int B = in_sizes[0] / TT;          // 4096
    lstm_mfma20_kernel<<<B / BT, NTH, 0, stream>>>(x, W_ih, W_hh, b_ih, b_hh,
                                                   W_out, b_out, out);
}

// Round 16
// 231.318 us; speedup vs baseline: 1.0972x; 1.0972x over previous
//
#include <hip/hip_runtime.h>
#include <math.h>

#define HID 50
#define TT  512
#define BT  16      // batch per block (= MFMA N)
#define NCW 7       // compute waves; w0..w5 = 2 tiles, w6 = 1 tile; wave 7 = chore
#define NTH 512     // 8 waves, 2 per SIMD (proven best: R24 = 181.5 µs)
#define HS  72      // H plane row stride in shorts (144 B, 16B-aligned)
#define L2E 1.44269504088896f
#define K2C 2.88539008177793f   // 2*log2(e)

typedef __attribute__((ext_vector_type(8))) short bf16x8;
typedef __attribute__((ext_vector_type(4))) float f32x4;

__device__ __forceinline__ unsigned short bf16_rtne(float f) {
    unsigned u = __float_as_uint(f);
    u = (u + 0x7FFFu + ((u >> 16) & 1u)) >> 16;
    return (unsigned short)u;
}
__device__ __forceinline__ float bf16_f32(unsigned short s) {
    return __uint_as_float(((unsigned)s) << 16);
}

// R28 = R24 (181.5 µs, session best) + ONE subtractive trim: wave 6 skips
// the pure-phantom tile 13 entirely (its 2 MFMAs + GATES computed provable
// zeros into never-read slots 57..60; those slots stay 0 from init).
// Wave-uniform wv<6 branch; no remapping, no new duties.
// STRUCTURE LESSONS (3 failed A/Bs): R25 straggler-merge 213 µs, R26
// 7-wave balanced 198 µs, R27 trans-balanced mixed-M 204 µs — R24's
// {6x2-tile + 1x1-tile + light chore, 2 waves/SIMD} is the local optimum;
// wave-level issue rebalancing is a refuted lever on this kernel.
// Carries: lgkm-only barrier (R20), unroll x2 + hoisted ptrs + cvt_pk
// (R21), chained MFMA (R23), ILP-2 tiles + shared B read (R24).
//
// Math (A rows pre-scaled by log2e for i,f,o / 2*log2e for g):
//   Ei=2^-i', Ef=2^-f', Eg=2^g', Eo=2^-o'
//   cs = [cs*(1+Ei)(1+Eg) + K2*(Eg-1)*(1+Ef)] * rcp((1+Ef)(1+Ei)(1+Eg))
//   Ec = 2^cs;  h = (Ec-1) * rcp((1+Eo)(1+Ec))
// K-slots: 0..49 = s*W_hh | 50 = (s*Wih)_hi (x_hi) | 51 = (s*bias)_hi (1.0)
//          52 = (s*Wih)_hi (x_lo) | 53 = (s*bias)_lo (1.0) | 54 = (s*Wih)_lo (x_hi)
//          55,56 = w6 phantom-h dump (h==0 there) | 57..63 = zero, never written
__global__ __launch_bounds__(NTH, 1) void lstm_mfma21_kernel(
    const float* __restrict__ x,      // [B, T]
    const float* __restrict__ W_ih,   // [200, 1]
    const float* __restrict__ W_hh,   // [200, 50]
    const float* __restrict__ b_ih,   // [200]
    const float* __restrict__ b_hh,   // [200]
    const float* __restrict__ W_out,  // [1, 50]
    const float* __restrict__ b_out,  // [1]
    float* __restrict__ out)          // [B, T]
{
    const int tid  = threadIdx.x;
    const int lane = tid & 63;
    const int wv   = tid >> 6;       // 0..7
    const int col  = lane & 15;      // A-m / B-n(batch) / D-col(batch)
    const int quad = lane >> 4;      // k-octet / D row-group

    __shared__ __align__(16) unsigned short Hh[2][BT][HS];

    // zero both H buffers (k-slots 55..63 + pads stay 0)
    for (int i = tid; i < 2 * BT * HS; i += NTH)
        (&Hh[0][0][0])[i] = 0;

    // persistent A fragments: [tile][kk] (single plane, PRE-SCALED rows)
    bf16x8 Ah[2][2];
    float cs0 = 0.f, cs1 = 0.f;                // 2*log2e * c per tile
    const int uoa = (wv * 2) * 4 + quad;
    const int uob = (wv * 2 + 1) * 4 + quad;
    const int uo2a = (uoa < HID) ? uoa : uoa + 5;   // w6: 50,51 -> 55,56
    const int uo2b = (uob < HID) ? uob : uob + 5;   // w6: unused (tile 13 skipped)

    if (wv < NCW) {
        #pragma unroll
        for (int i = 0; i < 2; ++i) {
            const int gh  = (wv * 2 + i) * 16 + col;   // g^ row
            const int u   = gh >> 2;
            const int ty  = gh & 3;
            const bool vl = (u < HID);
            const int og  = ty * HID + u;              // original gate row
            const float sc = (ty == 2) ? K2C : L2E;
            #pragma unroll
            for (int kk = 0; kk < 2; ++kk) {
                #pragma unroll
                for (int j = 0; j < 8; ++j) {
                    const int k = kk * 32 + quad * 8 + j;
                    float v = 0.f;
                    if (vl) {
                        if (k < HID)      v = sc * W_hh[og * HID + k];
                        else if (k == 50) v = sc * W_ih[og];
                        else if (k == 51) v = sc * (b_ih[og] + b_hh[og]);
                        else if (k == 52) v = sc * W_ih[og];
                        else if (k == 53) {
                            const float sb = sc * (b_ih[og] + b_hh[og]);
                            v = sb - bf16_f32(bf16_rtne(sb));
                        } else if (k == 54) {
                            const float sw = sc * W_ih[og];
                            v = sw - bf16_f32(bf16_rtne(sw));
                        }
                    }
                    Ah[i][kk][j] = (short)bf16_rtne(v);
                }
            }
        }
    } else {
        // chore wave: A row0 = hi(W_out), row1 = W_out - hi(W_out)
        #pragma unroll
        for (int kk = 0; kk < 2; ++kk) {
            #pragma unroll
            for (int j = 0; j < 8; ++j) {
                const int k = kk * 32 + quad * 8 + j;
                const float v = (k < HID) ? W_out[k] : 0.f;
                const unsigned short hi = bf16_rtne(v);
                short val = 0;
                if (col == 0)      val = (short)hi;
                else if (col == 1) val = (short)bf16_rtne(v - bf16_f32(hi));
                Ah[0][kk][j] = val;
                Ah[1][kk][j] = 0;
            }
        }
    }
    const float bo = b_out[0];
    float* yout = out + (size_t)blockIdx.x * BT * TT + (size_t)(lane & 15) * TT;

    // chore-wave x pipeline state (lanes 16..31 own batch b = lane-16)
    const int xb = (lane >= 16) ? (lane - 16) : 0;
    const float* xrow = x + (size_t)(blockIdx.x * BT + xb) * TT;
    float xa = 0.f;
    if (wv == NCW && lane >= 16 && lane < 32)
        xa = xrow[1];                            // x[b][1] for step t=0's write

    __syncthreads();    // zeroed H visible

    // buffer-0 slots for t=0: x_0 hi/lo + bias-1.0 markers (packed b32 writes)
    if (tid < BT) {
        const float x0 = x[(size_t)(blockIdx.x * BT + tid) * TT];
        const unsigned short hx = bf16_rtne(x0);
        const unsigned short lx = bf16_rtne(x0 - bf16_f32(hx));
        unsigned* row32 = (unsigned*)&Hh[0][tid][0];
        row32[25] = (unsigned)hx | (0x3F80u << 16);   // k=50,51
        row32[26] = (unsigned)lx | (0x3F80u << 16);   // k=52,53
        Hh[0][tid][54] = hx;                          // k=54
    }
    __syncthreads();

    // hoisted per-lane pointers (loop-invariant)
    const unsigned short* rdA = &Hh[0][col][quad * 8];   // read plane 0
    const unsigned short* rdB = &Hh[1][col][quad * 8];   // read plane 1
    unsigned short* wrA0 = &Hh[1][col][uo2a];            // write when reading 0
    unsigned short* wrA1 = &Hh[1][col][uo2b];
    unsigned short* wrB0 = &Hh[0][col][uo2a];            // write when reading 1
    unsigned short* wrB1 = &Hh[0][col][uo2b];
    unsigned* xwA = (unsigned*)&Hh[1][xb][0];
    unsigned* xwB = (unsigned*)&Hh[0][xb][0];
    const f32x4 z = {0.f, 0.f, 0.f, 0.f};

#define GATES(ACC, CS, HOUT)                                                  \
    do {                                                                      \
        const float Ei = __builtin_amdgcn_exp2f(-(ACC).x);                    \
        const float Ef = __builtin_amdgcn_exp2f(-(ACC).y);                    \
        const float Eg = __builtin_amdgcn_exp2f((ACC).z);                     \
        const float Eo = __builtin_amdgcn_exp2f(-(ACC).w);                    \
        const float DIG = (1.f + Ei) * (1.f + Eg);                            \
        const float DF  = 1.f + Ef;                                           \
        const float t1  = fmaf(K2C, Eg, -K2C);                                \
        const float num = fmaf((CS), DIG, t1 * DF);                           \
        (CS) = num * __builtin_amdgcn_rcpf(DF * DIG);                         \
        const float Ec = __builtin_amdgcn_exp2f(CS);                          \
        (HOUT) = (Ec - 1.f) *                                                 \
                 __builtin_amdgcn_rcpf((1.f + Eo) * (1.f + Ec));              \
    } while (0)

#define LSTM_STEP(RD, WR0, WR1, XW, TI)                                       \
    do {                                                                      \
        const bf16x8 B0 = *(const bf16x8*)(RD);                               \
        const bf16x8 B1 = *(const bf16x8*)((RD) + 32);                        \
        if (wv < 6) {                                                         \
            f32x4 a0 = __builtin_amdgcn_mfma_f32_16x16x32_bf16(Ah[0][0], B0, z, 0, 0, 0); \
            f32x4 a1 = __builtin_amdgcn_mfma_f32_16x16x32_bf16(Ah[1][0], B0, z, 0, 0, 0); \
            a0 = __builtin_amdgcn_mfma_f32_16x16x32_bf16(Ah[0][1], B1, a0, 0, 0, 0); \
            a1 = __builtin_amdgcn_mfma_f32_16x16x32_bf16(Ah[1][1], B1, a1, 0, 0, 0); \
            float h0, h1;                                                     \
            GATES(a0, cs0, h0);                                               \
            GATES(a1, cs1, h1);                                               \
            unsigned hpk;                                                     \
            asm("v_cvt_pk_bf16_f32 %0, %1, %2" : "=v"(hpk) : "v"(h0), "v"(h1)); \
            *(WR0) = (unsigned short)(hpk & 0xFFFFu);                         \
            *(WR1) = (unsigned short)(hpk >> 16);                             \
        } else if (wv == 6) {                                                 \
            /* tile 12 only; tile 13 is pure phantom -> skipped */            \
            f32x4 a0 = __builtin_amdgcn_mfma_f32_16x16x32_bf16(Ah[0][0], B0, z, 0, 0, 0); \
            a0 = __builtin_amdgcn_mfma_f32_16x16x32_bf16(Ah[0][1], B1, a0, 0, 0, 0); \
            float h0;                                                         \
            GATES(a0, cs0, h0);                                               \
            unsigned hpk;                                                     \
            asm("v_cvt_pk_bf16_f32 %0, %1, %2" : "=v"(hpk) : "v"(h0), "v"(h0)); \
            *(WR0) = (unsigned short)(hpk & 0xFFFFu);                         \
        } else {                                                              \
            if (lane >= 16 && lane < 32) {                                    \
                const unsigned short hx = bf16_rtne(xa);                      \
                const unsigned short lx = bf16_rtne(xa - bf16_f32(hx));       \
                (XW)[25] = (unsigned)hx | (0x3F80u << 16);                    \
                (XW)[26] = (unsigned)lx | (0x3F80u << 16);                    \
                ((unsigned short*)(XW))[54] = hx;                             \
                xa = xrow[((TI) + 2 < TT) ? (TI) + 2 : TT - 1];               \
            }                                                                 \
            f32x4 a0 = __builtin_amdgcn_mfma_f32_16x16x32_bf16(Ah[0][0], B0, z, 0, 0, 0); \
            a0 = __builtin_amdgcn_mfma_f32_16x16x32_bf16(Ah[0][1], B1, a0, 0, 0, 0); \
            if (lane < 16 && (TI) > 0)                                        \
                yout[(TI) - 1] = a0.x + a0.y + bo;                            \
        }                                                                     \
    } while (0)

    for (int t = 0; t < TT; t += 2) {
        LSTM_STEP(rdA, wrA0, wrA1, xwA, t);        // read plane 0, write plane 1
        asm volatile("s_waitcnt lgkmcnt(0)\n\ts_barrier" ::: "memory");
        LSTM_STEP(rdB, wrB0, wrB1, xwB, t + 1);    // read plane 1, write plane 0
        asm volatile("s_waitcnt lgkmcnt(0)\n\ts_barrier" ::: "memory");
    }
#undef LSTM_STEP
#undef GATES

    // epilogue: y_{TT-1} from plane 0 (h_{511})
    if (wv == NCW) {
        const bf16x8 B0 = *(const bf16x8*)rdA;
        const bf16x8 B1 = *(const bf16x8*)(rdA + 32);
        f32x4 a0 = __builtin_amdgcn_mfma_f32_16x16x32_bf16(Ah[0][0], B0, z, 0, 0, 0);
        a0 = __builtin_amdgcn_mfma_f32_16x16x32_bf16(Ah[0][1], B1, a0, 0, 0, 0);
        if (lane < 16)
            yout[TT - 1] = a0.x + a0.y + bo;
    }
}

extern "C" void kernel_launch(void* const* d_in, const int* in_sizes, int n_in,
                              void* d_out, int out_size, void* d_ws, size_t ws_size,
                              hipStream_t stream) {
    const float* x     = (const float*)d_in[0];
    const float* W_ih  = (const float*)d_in[1];
    const float* W_hh  = (const float*)d_in[2];
    const float* b_ih  = (const float*)d_in[3];
    const float* b_hh  = (const float*)d_in[4];
    const float* W_out = (const float*)d_in[5];
    const float* b_out = (const float*)d_in[6];
    float* out = (float*)d_out;

    const int B = in_sizes[0] / TT;          // 4096
    lstm_mfma21_kernel<<<B / BT, NTH, 0, stream>>>(x, W_ih, W_hh, b_ih, b_hh,
                                                   W_out, b_out, out);
}